// Round 2
// baseline (387.785 us; speedup 1.0000x reference)
//
#include <hip/hip_runtime.h>
#include <cstdint>
#include <cmath>

#define B_ 4
#define H_ 256
#define C_ 80
#define TX_ 256
#define TY_ 1024
#define NEGF (-1e9f)
#define NEGD (-1e9)

// output layout (floats): o_en_ex [B,H,TY] | logp [B,TX,TY] | attn [B,TX,TY] | dr [B,TX]
#define OFF_LOGP (B_*H_*TY_)
#define OFF_ATTN (OFF_LOGP + B_*TX_*TY_)
#define OFF_DR   (OFF_ATTN + B_*TX_*TY_)

typedef __attribute__((address_space(3))) void* lds_ptr_t;
typedef const __attribute__((address_space(1))) void* glb_ptr_t;

// ---------------------------------------------------------------------------
// Kernel A: logp[b,x,t] = -0.5*mean_c((y-mu)^2 * exp(-2 ls)) - 0.5*mean_c(ls)
// Also writes masked+transposed lpT[b,t,x] into the attn output region
// (scratch until k_attn overwrites it).  f64 accumulate to track the np ref.
// ---------------------------------------------------------------------------
__global__ __launch_bounds__(256) void k_logp(
    const float* __restrict__ mu, const float* __restrict__ ls,
    const float* __restrict__ y, const int* __restrict__ xlp,
    const int* __restrict__ ylp, float* __restrict__ logp_out,
    float* __restrict__ lpT)
{
  const int b  = blockIdx.y;
  const int x0 = blockIdx.x * 4;     // 4 x's per block
  const int tid = threadIdx.x;
  __shared__ double s_mu[4][C_];
  __shared__ double s_w[4][C_];
  __shared__ double s_t0[4];
  for (int i = tid; i < 4 * C_; i += 256) {
    int xi = i / C_, c = i - xi * C_;
    double m = (double)mu[(b * C_ + c) * TX_ + x0 + xi];
    double l = (double)ls[(b * C_ + c) * TX_ + x0 + xi];
    s_mu[xi][c] = m;
    s_w[xi][c]  = exp(-2.0 * l);
  }
  if (tid < 4) {
    double s = 0.0;
    for (int c = 0; c < C_; ++c) s += (double)ls[(b * C_ + c) * TX_ + x0 + tid];
    s_t0[tid] = -0.5 * (s * (1.0 / C_));
  }
  __syncthreads();

  const int t0 = tid * 4;
  double acc[4][4];
#pragma unroll
  for (int xi = 0; xi < 4; ++xi)
#pragma unroll
    for (int k = 0; k < 4; ++k) acc[xi][k] = 0.0;

  const float4* yp = (const float4*)(y + (size_t)b * C_ * TY_) + tid;
#pragma unroll 4
  for (int c = 0; c < C_; ++c) {
    float4 yv = yp[c * (TY_ / 4)];
    double y0 = yv.x, y1 = yv.y, y2 = yv.z, y3 = yv.w;
#pragma unroll
    for (int xi = 0; xi < 4; ++xi) {
      double m = s_mu[xi][c], w = s_w[xi][c];
      double d0 = y0 - m, d1 = y1 - m, d2 = y2 - m, d3 = y3 - m;
      acc[xi][0] = fma(d0 * d0, w, acc[xi][0]);
      acc[xi][1] = fma(d1 * d1, w, acc[xi][1]);
      acc[xi][2] = fma(d2 * d2, w, acc[xi][2]);
      acc[xi][3] = fma(d3 * d3, w, acc[xi][3]);
    }
  }

  const int xlen = xlp[b], ylen = ylp[b];
#pragma unroll
  for (int xi = 0; xi < 4; ++xi) {
    int x = x0 + xi;
    double c0 = s_t0[xi];
    float r[4];
#pragma unroll
    for (int k = 0; k < 4; ++k)
      r[k] = (float)(acc[xi][k] * (-0.5 / C_) + c0);
    *(float4*)&logp_out[((size_t)(b * TX_ + x)) * TY_ + t0] =
        make_float4(r[0], r[1], r[2], r[3]);
    bool xm = x < xlen;
#pragma unroll
    for (int k = 0; k < 4; ++k) {
      float v = (xm && (t0 + k) < ylen) ? r[k] : NEGF;
      lpT[((size_t)(b * TY_) + t0 + k) * TX_ + x] = v;
    }
  }
}

// ---------------------------------------------------------------------------
// Kernel B: Viterbi DP. One wave64 per batch; lane holds x = 4*lane+j in f64.
// Columns streamed via global_load_lds DMA into a 16-slot LDS ring with
// manual fine-grained vmcnt waits (compiler can't track DMA->LDS deps, so it
// won't serialize).  LDS->reg staged 4 columns ahead (r[4], unroll 4).
// Diag bits packed column-major in LDS; backward = run-length bit walk.
// ---------------------------------------------------------------------------
__global__ __launch_bounds__(64) void k_dp(
    const float* __restrict__ lpT, const int* __restrict__ xlp,
    const int* __restrict__ ylp, float* __restrict__ dr_out,
    int* __restrict__ cum_ws, int* __restrict__ xt_ws)
{
  const int b = blockIdx.x;
  const int lane = threadIdx.x;
  __shared__ float ring[16 * TX_];      // 16 column slots, 1KB each
  __shared__ uint32_t bits[TX_][33];
  __shared__ uint32_t dur[TX_];

  const float* gb = lpT + (size_t)b * TY_ * TX_;  // column t at gb + t*TX_

#pragma unroll
  for (int j = 0; j < 4; ++j) dur[4 * lane + j] = 0;

  // prologue: fill all 16 ring slots (cols 0..15), one DMA each (1KB/instr)
#pragma unroll
  for (int s = 0; s < 16; ++s) {
    __builtin_amdgcn_global_load_lds((glb_ptr_t)(gb + s * TX_ + 4 * lane),
                                     (lds_ptr_t)(&ring[s * TX_]), 16, 0, 0);
  }
  // vmcnt(12): cols 0..3 landed (12 younger may be outstanding)
  __builtin_amdgcn_s_waitcnt(0x0F7C);
  float4 r[4];
#pragma unroll
  for (int j = 0; j < 4; ++j)
    r[j] = *(const float4*)&ring[j * TX_ + 4 * lane];

  double v0 = (lane == 0) ? 0.0 : NEGD, v1 = NEGD, v2 = NEGD, v3 = NEGD;
  double sh = NEGD;                     // shfl_up(v3) from previous iter
  uint32_t b0 = 0, b1 = 0, b2 = 0, b3 = 0;

#pragma unroll 4
  for (int t = 0; t < TY_; ++t) {
    float4 c = r[t & 3];
    double vs0 = (lane == 0) ? NEGD : sh;
    uint32_t bit = 1u << (t & 31);
    if (vs0 > v0) b0 |= bit;            // diag = v_shift > v (pre-update)
    if (v0 > v1)  b1 |= bit;
    if (v1 > v2)  b2 |= bit;
    if (v2 > v3)  b3 |= bit;
    double nv3 = (double)c.w + fmax(v3, v2);   // v3 first -> shfl issues early
    sh = __shfl_up(nv3, 1);
    double nv2 = (double)c.z + fmax(v2, v1);
    double nv1 = (double)c.y + fmax(v1, v0);
    double nv0 = (double)c.x + fmax(v0, vs0);
    v0 = nv0; v1 = nv1; v2 = nv2; v3 = nv3;
    if ((t & 31) == 31) {
      int w = t >> 5;
      bits[4 * lane + 0][w] = b0; bits[4 * lane + 1][w] = b1;
      bits[4 * lane + 2][w] = b2; bits[4 * lane + 3][w] = b3;
      b0 = b1 = b2 = b3 = 0;
    }
    // ---- pipeline maintenance ----
    // vmcnt(11): DMA for col t+4 complete (cols t+5..t+15 may be in flight)
    __builtin_amdgcn_s_waitcnt(0x0F7B);
    r[t & 3] = *(const float4*)&ring[((t + 4) & 15) * TX_ + 4 * lane];
    // issue DMA for col t+16 into slot (t+16)&15 == t&15 (clamped in-bounds;
    // values past col 1023 are never consumed)
    int tc = (t + 16 < TY_) ? (t + 16) : (TY_ - 1);
    __builtin_amdgcn_global_load_lds((glb_ptr_t)(gb + tc * TX_ + 4 * lane),
                                     (lds_ptr_t)(&ring[(t & 15) * TX_]),
                                     16, 0, 0);
  }
  __syncthreads();

  const int xlen = xlp[b], ylen = ylp[b];
  if (lane == 0) {
    int idx = xlen - 1;
    int t = ylen - 1;
    while (t >= 0) {
      if (idx == 0) { dur[0] += (uint32_t)(t + 1); break; }
      int w = t >> 5, rr = t & 31;
      uint32_t word = bits[idx][w];
      word &= (rr == 31) ? 0xffffffffu : ((1u << (rr + 1)) - 1u);
      while (word == 0 && w > 0) { --w; word = bits[idx][w]; }
      if (word == 0) { dur[idx] += (uint32_t)(t + 1); break; }
      int bitpos = 31 - __builtin_clz(word);
      int tp = (w << 5) | bitpos;          // step where diag fires -> decrement
      dur[idx] += (uint32_t)(t - tp + 1);
      --idx;
      t = tp - 1;
    }
  }
  __syncthreads();

  // wave-wide inclusive scan of durations -> cum, dr, and t->x scatter map
  uint32_t d0 = dur[4 * lane], d1 = dur[4 * lane + 1];
  uint32_t d2 = dur[4 * lane + 2], d3 = dur[4 * lane + 3];
  uint32_t own = d0 + d1 + d2 + d3;
  uint32_t s = own;
#pragma unroll
  for (int off = 1; off < 64; off <<= 1) {
    uint32_t n = __shfl_up(s, off);
    if (lane >= off) s += n;
  }
  uint32_t base = s - own;
  uint32_t c0 = base + d0, c1 = c0 + d1, c2 = c1 + d2, c3 = c2 + d3;
  int x = 4 * lane;
  cum_ws[b * TX_ + x]     = (int)c0;
  cum_ws[b * TX_ + x + 1] = (int)c1;
  cum_ws[b * TX_ + x + 2] = (int)c2;
  cum_ws[b * TX_ + x + 3] = (int)c3;
  dr_out[b * TX_ + x]     = (float)d0;
  dr_out[b * TX_ + x + 1] = (float)d1;
  dr_out[b * TX_ + x + 2] = (float)d2;
  dr_out[b * TX_ + x + 3] = (float)d3;
  int* xt = xt_ws + b * TY_;
  for (uint32_t t = c0 - d0; t < c0; ++t) xt[t] = x;
  for (uint32_t t = c1 - d1; t < c1; ++t) xt[t] = x + 1;
  for (uint32_t t = c2 - d2; t < c2; ++t) xt[t] = x + 2;
  for (uint32_t t = c3 - d3; t < c3; ++t) xt[t] = x + 3;
}

// ---------------------------------------------------------------------------
// Kernel C: attn[b,x,t] = (cum[x-1] <= t < cum[x])  (== MAS path == gen_path)
// ---------------------------------------------------------------------------
__global__ __launch_bounds__(256) void k_attn(
    const int* __restrict__ cum_ws, float* __restrict__ attn)
{
  const int b = blockIdx.y, x = blockIdx.x, tid = threadIdx.x;
  int hi = cum_ws[b * TX_ + x];
  int lo = (x > 0) ? cum_ws[b * TX_ + x - 1] : 0;
  int t0 = tid * 4;
  float4 v;
  v.x = (t0     >= lo && t0     < hi) ? 1.f : 0.f;
  v.y = (t0 + 1 >= lo && t0 + 1 < hi) ? 1.f : 0.f;
  v.z = (t0 + 2 >= lo && t0 + 2 < hi) ? 1.f : 0.f;
  v.w = (t0 + 3 >= lo && t0 + 3 < hi) ? 1.f : 0.f;
  *(float4*)&attn[((size_t)(b * TX_ + x)) * TY_ + t0] = v;
}

// ---------------------------------------------------------------------------
// Kernel D: o_en_ex[b,h,t] = t < ylen ? en[b,h,xt[b,t]] : 0   (path is one-hot)
// ---------------------------------------------------------------------------
__global__ __launch_bounds__(256) void k_gather(
    const float* __restrict__ en, const int* __restrict__ xt_ws,
    const int* __restrict__ ylp, float* __restrict__ oen)
{
  const int b = blockIdx.y, h = blockIdx.x, tid = threadIdx.x;
  __shared__ float row[TX_];
  row[tid] = en[((size_t)(b * H_ + h)) * TX_ + tid];
  __syncthreads();
  const int ylen = ylp[b];
  int t0 = tid * 4;
  int4 xi = *(const int4*)&xt_ws[b * TY_ + t0];
  float4 v;
  v.x = (t0     < ylen) ? row[xi.x & (TX_ - 1)] : 0.f;
  v.y = (t0 + 1 < ylen) ? row[xi.y & (TX_ - 1)] : 0.f;
  v.z = (t0 + 2 < ylen) ? row[xi.z & (TX_ - 1)] : 0.f;
  v.w = (t0 + 3 < ylen) ? row[xi.w & (TX_ - 1)] : 0.f;
  *(float4*)&oen[((size_t)(b * H_ + h)) * TY_ + t0] = v;
}

extern "C" void kernel_launch(void* const* d_in, const int* in_sizes, int n_in,
                              void* d_out, int out_size, void* d_ws, size_t ws_size,
                              hipStream_t stream)
{
  const float* en = (const float*)d_in[0];
  const float* mu = (const float*)d_in[1];
  const float* ls = (const float*)d_in[2];
  const float* y  = (const float*)d_in[3];
  const int*   xl = (const int*)d_in[4];
  const int*   yl = (const int*)d_in[5];

  float* out  = (float*)d_out;
  float* oen  = out;             // [B,H,TY]
  float* logp = out + OFF_LOGP;  // [B,TX,TY]
  float* attn = out + OFF_ATTN;  // [B,TX,TY] (doubles as lpT scratch first)
  float* dr   = out + OFF_DR;    // [B,TX]

  int* cum = (int*)d_ws;         // B*TX ints
  int* xt  = cum + B_ * TX_;     // B*TY ints

  k_logp  <<<dim3(TX_ / 4, B_), 256, 0, stream>>>(mu, ls, y, xl, yl, logp, attn);
  k_dp    <<<B_,              64, 0, stream>>>(attn, xl, yl, dr, cum, xt);
  k_attn  <<<dim3(TX_, B_),  256, 0, stream>>>(cum, attn);
  k_gather<<<dim3(H_, B_),   256, 0, stream>>>(en, xt, yl, oen);
}

// Round 3
// 228.925 us; speedup vs baseline: 1.6939x; 1.6939x over previous
//
#include <hip/hip_runtime.h>
#include <cstdint>
#include <cmath>

#define B_ 4
#define H_ 256
#define C_ 80
#define TX_ 256
#define TY_ 1024
#define NEGF (-1e9f)
#define NEGD (-1e9)

// output layout (floats): o_en_ex [B,H,TY] | logp [B,TX,TY] | attn [B,TX,TY] | dr [B,TX]
#define OFF_LOGP (B_*H_*TY_)
#define OFF_ATTN (OFF_LOGP + B_*TX_*TY_)
#define OFF_DR   (OFF_ATTN + B_*TX_*TY_)

typedef __attribute__((address_space(3))) void* lds_ptr_t;
typedef const __attribute__((address_space(1))) void* glb_ptr_t;

// ---------------------------------------------------------------------------
// Kernel A: logp[b,x,t] = -0.5*mean_c((y-mu)^2 * exp(-2 ls)) - 0.5*mean_c(ls)
// Also writes masked+transposed lpT[b,t,x] into the attn output region
// (scratch until k_attn overwrites it).  f64 accumulate to track the np ref.
// ---------------------------------------------------------------------------
__global__ __launch_bounds__(256) void k_logp(
    const float* __restrict__ mu, const float* __restrict__ ls,
    const float* __restrict__ y, const int* __restrict__ xlp,
    const int* __restrict__ ylp, float* __restrict__ logp_out,
    float* __restrict__ lpT)
{
  const int b  = blockIdx.y;
  const int x0 = blockIdx.x * 4;     // 4 x's per block
  const int tid = threadIdx.x;
  __shared__ double s_mu[4][C_];
  __shared__ double s_w[4][C_];
  __shared__ double s_t0[4];
  for (int i = tid; i < 4 * C_; i += 256) {
    int xi = i / C_, c = i - xi * C_;
    double m = (double)mu[(b * C_ + c) * TX_ + x0 + xi];
    double l = (double)ls[(b * C_ + c) * TX_ + x0 + xi];
    s_mu[xi][c] = m;
    s_w[xi][c]  = exp(-2.0 * l);
  }
  if (tid < 4) {
    double s = 0.0;
    for (int c = 0; c < C_; ++c) s += (double)ls[(b * C_ + c) * TX_ + x0 + tid];
    s_t0[tid] = -0.5 * (s * (1.0 / C_));
  }
  __syncthreads();

  const int t0 = tid * 4;
  double acc[4][4];
#pragma unroll
  for (int xi = 0; xi < 4; ++xi)
#pragma unroll
    for (int k = 0; k < 4; ++k) acc[xi][k] = 0.0;

  const float4* yp = (const float4*)(y + (size_t)b * C_ * TY_) + tid;
#pragma unroll 4
  for (int c = 0; c < C_; ++c) {
    float4 yv = yp[c * (TY_ / 4)];
    double y0 = yv.x, y1 = yv.y, y2 = yv.z, y3 = yv.w;
#pragma unroll
    for (int xi = 0; xi < 4; ++xi) {
      double m = s_mu[xi][c], w = s_w[xi][c];
      double d0 = y0 - m, d1 = y1 - m, d2 = y2 - m, d3 = y3 - m;
      acc[xi][0] = fma(d0 * d0, w, acc[xi][0]);
      acc[xi][1] = fma(d1 * d1, w, acc[xi][1]);
      acc[xi][2] = fma(d2 * d2, w, acc[xi][2]);
      acc[xi][3] = fma(d3 * d3, w, acc[xi][3]);
    }
  }

  const int xlen = xlp[b], ylen = ylp[b];
#pragma unroll
  for (int xi = 0; xi < 4; ++xi) {
    int x = x0 + xi;
    double c0 = s_t0[xi];
    float r[4];
#pragma unroll
    for (int k = 0; k < 4; ++k)
      r[k] = (float)(acc[xi][k] * (-0.5 / C_) + c0);
    *(float4*)&logp_out[((size_t)(b * TX_ + x)) * TY_ + t0] =
        make_float4(r[0], r[1], r[2], r[3]);
    bool xm = x < xlen;
#pragma unroll
    for (int k = 0; k < 4; ++k) {
      float v = (xm && (t0 + k) < ylen) ? r[k] : NEGF;
      lpT[((size_t)(b * TY_) + t0 + k) * TX_ + x] = v;
    }
  }
}

// ---------------------------------------------------------------------------
// Kernel B: Viterbi DP, producer-consumer. 2 waves/block: wave 1 DMAs the
// next 16 columns into an LDS double buffer (drain happens at the compiler's
// forced vmcnt(0)-before-barrier — once per chunk, overlapped with wave 0's
// compute on the current chunk). Wave 0 runs the DP from LDS.
// LDS (64KB exactly): words [0,8192) = column ring (2 x 16 cols x 1KB),
// reused for dur[] after the main loop; words [8192,16384) = diag bits,
// word-major uint4: bits4[w][lane] = bits of x=4*lane..4*lane+3 at t-word w.
// ---------------------------------------------------------------------------
__global__ __launch_bounds__(128) void k_dp(
    const float* __restrict__ lpT, const int* __restrict__ xlp,
    const int* __restrict__ ylp, float* __restrict__ dr_out,
    int* __restrict__ cum_ws, int* __restrict__ xt_ws)
{
  const int b = blockIdx.x;
  const int lane = threadIdx.x & 63;
  const int wid  = threadIdx.x >> 6;
  __shared__ uint32_t smem[16384];           // 64 KB
  float* smemf = (float*)smem;
#define BITS_OFF 8192

  const float* gb = lpT + (size_t)b * TY_ * TX_;  // column t at gb + t*TX_

  // prologue: producer fills buffer 0 with chunk 0 (cols 0..15)
  if (wid == 1) {
#pragma unroll
    for (int i = 0; i < 16; ++i)
      __builtin_amdgcn_global_load_lds((glb_ptr_t)(gb + i * TX_ + 4 * lane),
                                       (lds_ptr_t)(&smemf[i * 256]), 16, 0, 0);
  }
  __syncthreads();

  double v0 = (lane == 0) ? 0.0 : NEGD, v1 = NEGD, v2 = NEGD, v3 = NEGD;
  double sh = NEGD;                     // shfl_up(v3) from previous iter
  uint32_t b0 = 0, b1 = 0, b2 = 0, b3 = 0;

  for (int c = 0; c < TY_ / 16; ++c) {
    if (wid == 1) {
      // produce chunk c+1 into buffer (c+1)&1; barrier drains the DMAs
      if (c + 1 < TY_ / 16) {
        const float* src = gb + (size_t)(c + 1) * 16 * TX_;
        const uint32_t nbase = ((c + 1) & 1) * 4096;
#pragma unroll
        for (int i = 0; i < 16; ++i)
          __builtin_amdgcn_global_load_lds(
              (glb_ptr_t)(src + i * TX_ + 4 * lane),
              (lds_ptr_t)(&smemf[nbase + i * 256]), 16, 0, 0);
      }
    } else if (wid == 0) {
      const uint32_t rbase = (c & 1) * 4096;
#pragma unroll
      for (int i = 0; i < 16; ++i) {
        const int t = c * 16 + i;
        float4 cl = *(const float4*)&smemf[rbase + i * 256 + 4 * lane];
        double vs0 = (lane == 0) ? NEGD : sh;
        uint32_t bit = 1u << (t & 31);
        if (vs0 > v0) b0 |= bit;        // diag = v_shift > v (pre-update)
        if (v0 > v1)  b1 |= bit;
        if (v1 > v2)  b2 |= bit;
        if (v2 > v3)  b3 |= bit;
        double nv3 = (double)cl.w + fmax(v3, v2);  // v3 first -> shfl early
        sh = __shfl_up(nv3, 1);
        double nv2 = (double)cl.z + fmax(v2, v1);
        double nv1 = (double)cl.y + fmax(v1, v0);
        double nv0 = (double)cl.x + fmax(v0, vs0);
        v0 = nv0; v1 = nv1; v2 = nv2; v3 = nv3;
        if ((t & 31) == 31) {
          int w = t >> 5;
          uint4 pk; pk.x = b0; pk.y = b1; pk.z = b2; pk.w = b3;
          *(uint4*)&smem[BITS_OFF + (w * 64 + lane) * 4] = pk;
          b0 = b1 = b2 = b3 = 0;
        }
      }
    }
    __syncthreads();
  }

  // dur[] aliases the (now dead) column ring
  uint32_t* dur = smem;
  for (int j = threadIdx.x; j < TX_; j += 128) dur[j] = 0;
  __syncthreads();

  const int xlen = xlp[b], ylen = ylp[b];
  if (threadIdx.x == 0) {
    int idx = xlen - 1;
    int t = ylen - 1;
    while (t >= 0) {
      if (idx == 0) { dur[0] += (uint32_t)(t + 1); break; }
      int w = t >> 5, rr = t & 31;
      uint32_t word = smem[BITS_OFF + (w * 64 + (idx >> 2)) * 4 + (idx & 3)];
      word &= (rr == 31) ? 0xffffffffu : ((1u << (rr + 1)) - 1u);
      while (word == 0 && w > 0) {
        --w;
        word = smem[BITS_OFF + (w * 64 + (idx >> 2)) * 4 + (idx & 3)];
      }
      if (word == 0) { dur[idx] += (uint32_t)(t + 1); break; }
      int bitpos = 31 - __builtin_clz(word);
      int tp = (w << 5) | bitpos;          // step where diag fires -> decrement
      dur[idx] += (uint32_t)(t - tp + 1);
      --idx;
      t = tp - 1;
    }
  }
  __syncthreads();

  if (wid == 0) {
    // wave-wide inclusive scan of durations -> cum, dr, and t->x scatter map
    uint32_t d0 = dur[4 * lane], d1 = dur[4 * lane + 1];
    uint32_t d2 = dur[4 * lane + 2], d3 = dur[4 * lane + 3];
    uint32_t own = d0 + d1 + d2 + d3;
    uint32_t s = own;
#pragma unroll
    for (int off = 1; off < 64; off <<= 1) {
      uint32_t n = __shfl_up(s, off);
      if (lane >= off) s += n;
    }
    uint32_t base = s - own;
    uint32_t c0 = base + d0, c1 = c0 + d1, c2 = c1 + d2, c3 = c2 + d3;
    int x = 4 * lane;
    cum_ws[b * TX_ + x]     = (int)c0;
    cum_ws[b * TX_ + x + 1] = (int)c1;
    cum_ws[b * TX_ + x + 2] = (int)c2;
    cum_ws[b * TX_ + x + 3] = (int)c3;
    dr_out[b * TX_ + x]     = (float)d0;
    dr_out[b * TX_ + x + 1] = (float)d1;
    dr_out[b * TX_ + x + 2] = (float)d2;
    dr_out[b * TX_ + x + 3] = (float)d3;
    int* xt = xt_ws + b * TY_;
    for (uint32_t t = c0 - d0; t < c0; ++t) xt[t] = x;
    for (uint32_t t = c1 - d1; t < c1; ++t) xt[t] = x + 1;
    for (uint32_t t = c2 - d2; t < c2; ++t) xt[t] = x + 2;
    for (uint32_t t = c3 - d3; t < c3; ++t) xt[t] = x + 3;
  }
}

// ---------------------------------------------------------------------------
// Kernel C: attn[b,x,t] = (cum[x-1] <= t < cum[x])  (== MAS path == gen_path)
// ---------------------------------------------------------------------------
__global__ __launch_bounds__(256) void k_attn(
    const int* __restrict__ cum_ws, float* __restrict__ attn)
{
  const int b = blockIdx.y, x = blockIdx.x, tid = threadIdx.x;
  int hi = cum_ws[b * TX_ + x];
  int lo = (x > 0) ? cum_ws[b * TX_ + x - 1] : 0;
  int t0 = tid * 4;
  float4 v;
  v.x = (t0     >= lo && t0     < hi) ? 1.f : 0.f;
  v.y = (t0 + 1 >= lo && t0 + 1 < hi) ? 1.f : 0.f;
  v.z = (t0 + 2 >= lo && t0 + 2 < hi) ? 1.f : 0.f;
  v.w = (t0 + 3 >= lo && t0 + 3 < hi) ? 1.f : 0.f;
  *(float4*)&attn[((size_t)(b * TX_ + x)) * TY_ + t0] = v;
}

// ---------------------------------------------------------------------------
// Kernel D: o_en_ex[b,h,t] = t < ylen ? en[b,h,xt[b,t]] : 0   (path is one-hot)
// ---------------------------------------------------------------------------
__global__ __launch_bounds__(256) void k_gather(
    const float* __restrict__ en, const int* __restrict__ xt_ws,
    const int* __restrict__ ylp, float* __restrict__ oen)
{
  const int b = blockIdx.y, h = blockIdx.x, tid = threadIdx.x;
  __shared__ float row[TX_];
  row[tid] = en[((size_t)(b * H_ + h)) * TX_ + tid];
  __syncthreads();
  const int ylen = ylp[b];
  int t0 = tid * 4;
  int4 xi = *(const int4*)&xt_ws[b * TY_ + t0];
  float4 v;
  v.x = (t0     < ylen) ? row[xi.x & (TX_ - 1)] : 0.f;
  v.y = (t0 + 1 < ylen) ? row[xi.y & (TX_ - 1)] : 0.f;
  v.z = (t0 + 2 < ylen) ? row[xi.z & (TX_ - 1)] : 0.f;
  v.w = (t0 + 3 < ylen) ? row[xi.w & (TX_ - 1)] : 0.f;
  *(float4*)&oen[((size_t)(b * H_ + h)) * TY_ + t0] = v;
}

extern "C" void kernel_launch(void* const* d_in, const int* in_sizes, int n_in,
                              void* d_out, int out_size, void* d_ws, size_t ws_size,
                              hipStream_t stream)
{
  const float* en = (const float*)d_in[0];
  const float* mu = (const float*)d_in[1];
  const float* ls = (const float*)d_in[2];
  const float* y  = (const float*)d_in[3];
  const int*   xl = (const int*)d_in[4];
  const int*   yl = (const int*)d_in[5];

  float* out  = (float*)d_out;
  float* oen  = out;             // [B,H,TY]
  float* logp = out + OFF_LOGP;  // [B,TX,TY]
  float* attn = out + OFF_ATTN;  // [B,TX,TY] (doubles as lpT scratch first)
  float* dr   = out + OFF_DR;    // [B,TX]

  int* cum = (int*)d_ws;         // B*TX ints
  int* xt  = cum + B_ * TX_;     // B*TY ints

  k_logp  <<<dim3(TX_ / 4, B_), 256, 0, stream>>>(mu, ls, y, xl, yl, logp, attn);
  k_dp    <<<B_,             128, 0, stream>>>(attn, xl, yl, dr, cum, xt);
  k_attn  <<<dim3(TX_, B_),  256, 0, stream>>>(cum, attn);
  k_gather<<<dim3(H_, B_),   256, 0, stream>>>(en, xt, yl, oen);
}

// Round 4
// 226.276 us; speedup vs baseline: 1.7138x; 1.0117x over previous
//
#include <hip/hip_runtime.h>
#include <cstdint>
#include <cmath>

#define B_ 4
#define H_ 256
#define C_ 80
#define TX_ 256
#define TY_ 1024
#define NEGF (-1e9f)
#define NEGD (-1e9)

// output layout (floats): o_en_ex [B,H,TY] | logp [B,TX,TY] | attn [B,TX,TY] | dr [B,TX]
#define OFF_LOGP (B_*H_*TY_)
#define OFF_ATTN (OFF_LOGP + B_*TX_*TY_)
#define OFF_DR   (OFF_ATTN + B_*TX_*TY_)

// ---------------------------------------------------------------------------
// Kernel A: logp[b,x,t] = -0.5*mean_c((y-mu)^2 * exp(-2 ls)) - 0.5*mean_c(ls)
// Also writes masked+transposed lpT[b,t,x] into the attn output region
// (scratch until k_attn overwrites it).  f64 accumulate (numerics identical
// to the passing R1-R3 versions).  lpT store staged through an LDS tile so
// each store is a 16B float4 row instead of 16 scattered dwords.
// ---------------------------------------------------------------------------
__global__ __launch_bounds__(256) void k_logp(
    const float* __restrict__ mu, const float* __restrict__ ls,
    const float* __restrict__ y, const int* __restrict__ xlp,
    const int* __restrict__ ylp, float* __restrict__ logp_out,
    float* __restrict__ lpT)
{
  const int b  = blockIdx.y;
  const int x0 = blockIdx.x * 4;     // 4 x's per block
  const int tid = threadIdx.x;
  __shared__ double s_mu[4][C_];
  __shared__ double s_w[4][C_];
  __shared__ double s_t0[4];
  __shared__ float tile[TY_][4];     // [t][xi] transposed tile, 16 KB
  for (int i = tid; i < 4 * C_; i += 256) {
    int xi = i / C_, c = i - xi * C_;
    double m = (double)mu[(b * C_ + c) * TX_ + x0 + xi];
    double l = (double)ls[(b * C_ + c) * TX_ + x0 + xi];
    s_mu[xi][c] = m;
    s_w[xi][c]  = exp(-2.0 * l);
  }
  if (tid < 4) {
    double s = 0.0;
    for (int c = 0; c < C_; ++c) s += (double)ls[(b * C_ + c) * TX_ + x0 + tid];
    s_t0[tid] = -0.5 * (s * (1.0 / C_));
  }
  __syncthreads();

  const int t0 = tid * 4;
  double acc[4][4];
#pragma unroll
  for (int xi = 0; xi < 4; ++xi)
#pragma unroll
    for (int k = 0; k < 4; ++k) acc[xi][k] = 0.0;

  const float4* yp = (const float4*)(y + (size_t)b * C_ * TY_) + tid;
#pragma unroll 4
  for (int c = 0; c < C_; ++c) {
    float4 yv = yp[c * (TY_ / 4)];
    double y0 = yv.x, y1 = yv.y, y2 = yv.z, y3 = yv.w;
#pragma unroll
    for (int xi = 0; xi < 4; ++xi) {
      double m = s_mu[xi][c], w = s_w[xi][c];
      double d0 = y0 - m, d1 = y1 - m, d2 = y2 - m, d3 = y3 - m;
      acc[xi][0] = fma(d0 * d0, w, acc[xi][0]);
      acc[xi][1] = fma(d1 * d1, w, acc[xi][1]);
      acc[xi][2] = fma(d2 * d2, w, acc[xi][2]);
      acc[xi][3] = fma(d3 * d3, w, acc[xi][3]);
    }
  }

  const int xlen = xlp[b], ylen = ylp[b];
#pragma unroll
  for (int xi = 0; xi < 4; ++xi) {
    int x = x0 + xi;
    double c0 = s_t0[xi];
    float r[4];
#pragma unroll
    for (int k = 0; k < 4; ++k)
      r[k] = (float)(acc[xi][k] * (-0.5 / C_) + c0);
    *(float4*)&logp_out[((size_t)(b * TX_ + x)) * TY_ + t0] =
        make_float4(r[0], r[1], r[2], r[3]);
    bool xm = x < xlen;
#pragma unroll
    for (int k = 0; k < 4; ++k)
      tile[t0 + k][xi] = (xm && (t0 + k) < ylen) ? r[k] : NEGF;
  }
  __syncthreads();

  float* dst = lpT + (size_t)b * TY_ * TX_ + x0;
  const float4* tp = (const float4*)tile;
#pragma unroll
  for (int k = 0; k < 4; ++k) {
    int t = tid + 256 * k;           // consecutive lanes -> consecutive t
    *(float4*)&dst[(size_t)t * TX_] = tp[t];
  }
}

// ---------------------------------------------------------------------------
// Kernel B: Viterbi DP, producer-consumer. 2 waves/block: wave 1 loads the
// next 16 columns into VGPRs with regular global_load_dwordx4 (up to 16
// outstanding — unlike LDS-DMA, which serialized at ~1 outstanding/wave in
// R2/R3), then ds_write_b128 into the LDS double buffer; the per-chunk
// barrier drain overlaps with wave 0's DP compute on the current chunk.
// LDS (64KB): words [0,8192) = column ring (2 x 16 cols x 1KB), reused for
// dur[] after the main loop; words [8192,16384) = diag bits, word-major
// uint4: bits4[w][lane] = bits of x=4*lane..4*lane+3 at t-word w.
// ---------------------------------------------------------------------------
__global__ __launch_bounds__(128) void k_dp(
    const float* __restrict__ lpT, const int* __restrict__ xlp,
    const int* __restrict__ ylp, float* __restrict__ dr_out,
    int* __restrict__ cum_ws, int* __restrict__ xt_ws)
{
  const int b = blockIdx.x;
  const int lane = threadIdx.x & 63;
  const int wid  = threadIdx.x >> 6;
  __shared__ uint32_t smem[16384];           // 64 KB
  float* smemf = (float*)smem;
#define BITS_OFF 8192

  const float* gb = lpT + (size_t)b * TY_ * TX_;  // column t at gb + t*TX_

  // prologue: producer fills buffer 0 with chunk 0 (cols 0..15)
  if (wid == 1) {
    const float4* src = (const float4*)gb + lane;
    float4 v[16];
#pragma unroll
    for (int i = 0; i < 16; ++i) v[i] = src[i * 64];
#pragma unroll
    for (int i = 0; i < 16; ++i)
      *(float4*)&smemf[i * 256 + 4 * lane] = v[i];
  }
  __syncthreads();

  double v0 = (lane == 0) ? 0.0 : NEGD, v1 = NEGD, v2 = NEGD, v3 = NEGD;
  double sh = NEGD;                     // shfl_up(v3) from previous iter
  uint32_t b0 = 0, b1 = 0, b2 = 0, b3 = 0;

  for (int c = 0; c < TY_ / 16; ++c) {
    if (wid == 1) {
      // produce chunk c+1 into buffer (c+1)&1; barrier drains the writes
      if (c + 1 < TY_ / 16) {
        const float4* src =
            (const float4*)(gb + (size_t)(c + 1) * 16 * TX_) + lane;
        float4 v[16];
#pragma unroll
        for (int i = 0; i < 16; ++i) v[i] = src[i * 64];
        const uint32_t nbase = ((c + 1) & 1) * 4096;
#pragma unroll
        for (int i = 0; i < 16; ++i)
          *(float4*)&smemf[nbase + i * 256 + 4 * lane] = v[i];
      }
    } else if (wid == 0) {
      const uint32_t rbase = (c & 1) * 4096;
#pragma unroll
      for (int i = 0; i < 16; ++i) {
        const int t = c * 16 + i;
        float4 cl = *(const float4*)&smemf[rbase + i * 256 + 4 * lane];
        double vs0 = (lane == 0) ? NEGD : sh;
        uint32_t bit = 1u << (t & 31);
        if (vs0 > v0) b0 |= bit;        // diag = v_shift > v (pre-update)
        if (v0 > v1)  b1 |= bit;
        if (v1 > v2)  b2 |= bit;
        if (v2 > v3)  b3 |= bit;
        double nv3 = (double)cl.w + fmax(v3, v2);  // v3 first -> shfl early
        sh = __shfl_up(nv3, 1);
        double nv2 = (double)cl.z + fmax(v2, v1);
        double nv1 = (double)cl.y + fmax(v1, v0);
        double nv0 = (double)cl.x + fmax(v0, vs0);
        v0 = nv0; v1 = nv1; v2 = nv2; v3 = nv3;
        if ((t & 31) == 31) {
          int w = t >> 5;
          uint4 pk; pk.x = b0; pk.y = b1; pk.z = b2; pk.w = b3;
          *(uint4*)&smem[BITS_OFF + (w * 64 + lane) * 4] = pk;
          b0 = b1 = b2 = b3 = 0;
        }
      }
    }
    __syncthreads();
  }

  // dur[] aliases the (now dead) column ring
  uint32_t* dur = smem;
  for (int j = threadIdx.x; j < TX_; j += 128) dur[j] = 0;
  __syncthreads();

  const int xlen = xlp[b], ylen = ylp[b];
  if (threadIdx.x == 0) {
    int idx = xlen - 1;
    int t = ylen - 1;
    while (t >= 0) {
      if (idx == 0) { dur[0] += (uint32_t)(t + 1); break; }
      int w = t >> 5, rr = t & 31;
      uint32_t word = smem[BITS_OFF + (w * 64 + (idx >> 2)) * 4 + (idx & 3)];
      word &= (rr == 31) ? 0xffffffffu : ((1u << (rr + 1)) - 1u);
      while (word == 0 && w > 0) {
        --w;
        word = smem[BITS_OFF + (w * 64 + (idx >> 2)) * 4 + (idx & 3)];
      }
      if (word == 0) { dur[idx] += (uint32_t)(t + 1); break; }
      int bitpos = 31 - __builtin_clz(word);
      int tp = (w << 5) | bitpos;          // step where diag fires -> decrement
      dur[idx] += (uint32_t)(t - tp + 1);
      --idx;
      t = tp - 1;
    }
  }
  __syncthreads();

  if (wid == 0) {
    // wave-wide inclusive scan of durations -> cum, dr, and t->x scatter map
    uint32_t d0 = dur[4 * lane], d1 = dur[4 * lane + 1];
    uint32_t d2 = dur[4 * lane + 2], d3 = dur[4 * lane + 3];
    uint32_t own = d0 + d1 + d2 + d3;
    uint32_t s = own;
#pragma unroll
    for (int off = 1; off < 64; off <<= 1) {
      uint32_t n = __shfl_up(s, off);
      if (lane >= off) s += n;
    }
    uint32_t base = s - own;
    uint32_t c0 = base + d0, c1 = c0 + d1, c2 = c1 + d2, c3 = c2 + d3;
    int x = 4 * lane;
    cum_ws[b * TX_ + x]     = (int)c0;
    cum_ws[b * TX_ + x + 1] = (int)c1;
    cum_ws[b * TX_ + x + 2] = (int)c2;
    cum_ws[b * TX_ + x + 3] = (int)c3;
    dr_out[b * TX_ + x]     = (float)d0;
    dr_out[b * TX_ + x + 1] = (float)d1;
    dr_out[b * TX_ + x + 2] = (float)d2;
    dr_out[b * TX_ + x + 3] = (float)d3;
    int* xt = xt_ws + b * TY_;
    for (uint32_t t = c0 - d0; t < c0; ++t) xt[t] = x;
    for (uint32_t t = c1 - d1; t < c1; ++t) xt[t] = x + 1;
    for (uint32_t t = c2 - d2; t < c2; ++t) xt[t] = x + 2;
    for (uint32_t t = c3 - d3; t < c3; ++t) xt[t] = x + 3;
  }
}

// ---------------------------------------------------------------------------
// Kernel C: attn[b,x,t] = (cum[x-1] <= t < cum[x])  (== MAS path == gen_path)
// ---------------------------------------------------------------------------
__global__ __launch_bounds__(256) void k_attn(
    const int* __restrict__ cum_ws, float* __restrict__ attn)
{
  const int b = blockIdx.y, x = blockIdx.x, tid = threadIdx.x;
  int hi = cum_ws[b * TX_ + x];
  int lo = (x > 0) ? cum_ws[b * TX_ + x - 1] : 0;
  int t0 = tid * 4;
  float4 v;
  v.x = (t0     >= lo && t0     < hi) ? 1.f : 0.f;
  v.y = (t0 + 1 >= lo && t0 + 1 < hi) ? 1.f : 0.f;
  v.z = (t0 + 2 >= lo && t0 + 2 < hi) ? 1.f : 0.f;
  v.w = (t0 + 3 >= lo && t0 + 3 < hi) ? 1.f : 0.f;
  *(float4*)&attn[((size_t)(b * TX_ + x)) * TY_ + t0] = v;
}

// ---------------------------------------------------------------------------
// Kernel D: o_en_ex[b,h,t] = t < ylen ? en[b,h,xt[b,t]] : 0   (path is one-hot)
// ---------------------------------------------------------------------------
__global__ __launch_bounds__(256) void k_gather(
    const float* __restrict__ en, const int* __restrict__ xt_ws,
    const int* __restrict__ ylp, float* __restrict__ oen)
{
  const int b = blockIdx.y, h = blockIdx.x, tid = threadIdx.x;
  __shared__ float row[TX_];
  row[tid] = en[((size_t)(b * H_ + h)) * TX_ + tid];
  __syncthreads();
  const int ylen = ylp[b];
  int t0 = tid * 4;
  int4 xi = *(const int4*)&xt_ws[b * TY_ + t0];
  float4 v;
  v.x = (t0     < ylen) ? row[xi.x & (TX_ - 1)] : 0.f;
  v.y = (t0 + 1 < ylen) ? row[xi.y & (TX_ - 1)] : 0.f;
  v.z = (t0 + 2 < ylen) ? row[xi.z & (TX_ - 1)] : 0.f;
  v.w = (t0 + 3 < ylen) ? row[xi.w & (TX_ - 1)] : 0.f;
  *(float4*)&oen[((size_t)(b * H_ + h)) * TY_ + t0] = v;
}

extern "C" void kernel_launch(void* const* d_in, const int* in_sizes, int n_in,
                              void* d_out, int out_size, void* d_ws, size_t ws_size,
                              hipStream_t stream)
{
  const float* en = (const float*)d_in[0];
  const float* mu = (const float*)d_in[1];
  const float* ls = (const float*)d_in[2];
  const float* y  = (const float*)d_in[3];
  const int*   xl = (const int*)d_in[4];
  const int*   yl = (const int*)d_in[5];

  float* out  = (float*)d_out;
  float* oen  = out;             // [B,H,TY]
  float* logp = out + OFF_LOGP;  // [B,TX,TY]
  float* attn = out + OFF_ATTN;  // [B,TX,TY] (doubles as lpT scratch first)
  float* dr   = out + OFF_DR;    // [B,TX]

  int* cum = (int*)d_ws;         // B*TX ints
  int* xt  = cum + B_ * TX_;     // B*TY ints

  k_logp  <<<dim3(TX_ / 4, B_), 256, 0, stream>>>(mu, ls, y, xl, yl, logp, attn);
  k_dp    <<<B_,             128, 0, stream>>>(attn, xl, yl, dr, cum, xt);
  k_attn  <<<dim3(TX_, B_),  256, 0, stream>>>(cum, attn);
  k_gather<<<dim3(H_, B_),   256, 0, stream>>>(en, xt, yl, oen);
}

// Round 5
// 206.641 us; speedup vs baseline: 1.8766x; 1.0950x over previous
//
#include <hip/hip_runtime.h>
#include <cstdint>
#include <cmath>

#define B_ 4
#define H_ 256
#define C_ 80
#define TX_ 256
#define TY_ 1024
#define NEGF (-1e9f)
#define NEGD (-1e9)

// output layout (floats): o_en_ex [B,H,TY] | logp [B,TX,TY] | attn [B,TX,TY] | dr [B,TX]
#define OFF_LOGP (B_*H_*TY_)
#define OFF_ATTN (OFF_LOGP + B_*TX_*TY_)
#define OFF_DR   (OFF_ATTN + B_*TX_*TY_)

// __shfl_up(x,1) as pure VALU: DPP wave_shr:1 (ctrl 0x138) on both f64
// halves; lane 0 receives the `old` operand = NEGD. No LDS op -> the serial
// DP recurrence no longer forces lgkmcnt(0) (which drained the prefetched
// column ds_reads every iteration in R1-R4 = ~300 cyc/iter).
__device__ __forceinline__ double dpp_shr1_negfill(double x) {
  union { double d; int i[2]; } u, o, r;
  u.d = x; o.d = NEGD;
  r.i[0] = __builtin_amdgcn_update_dpp(o.i[0], u.i[0], 0x138, 0xf, 0xf, false);
  r.i[1] = __builtin_amdgcn_update_dpp(o.i[1], u.i[1], 0x138, 0xf, 0xf, false);
  return r.d;
}

// ---------------------------------------------------------------------------
// Kernel A: logp[b,x,t] = -0.5*mean_c((y-mu)^2 * exp(-2 ls)) - 0.5*mean_c(ls)
// Also writes masked+transposed lpT[b,t,x] into the attn output region
// (scratch until k_epi overwrites it).  f64 accumulate (numerics identical
// to the passing R1-R4 versions).
// ---------------------------------------------------------------------------
__global__ __launch_bounds__(256) void k_logp(
    const float* __restrict__ mu, const float* __restrict__ ls,
    const float* __restrict__ y, const int* __restrict__ xlp,
    const int* __restrict__ ylp, float* __restrict__ logp_out,
    float* __restrict__ lpT)
{
  const int b  = blockIdx.y;
  const int x0 = blockIdx.x * 4;     // 4 x's per block
  const int tid = threadIdx.x;
  __shared__ double s_mu[4][C_];
  __shared__ double s_w[4][C_];
  __shared__ double s_t0[4];
  __shared__ float tile[TY_][4];     // [t][xi] transposed tile, 16 KB
  for (int i = tid; i < 4 * C_; i += 256) {
    int xi = i / C_, c = i - xi * C_;
    double m = (double)mu[(b * C_ + c) * TX_ + x0 + xi];
    double l = (double)ls[(b * C_ + c) * TX_ + x0 + xi];
    s_mu[xi][c] = m;
    s_w[xi][c]  = exp(-2.0 * l);
  }
  if (tid < 4) {
    double s = 0.0;
    for (int c = 0; c < C_; ++c) s += (double)ls[(b * C_ + c) * TX_ + x0 + tid];
    s_t0[tid] = -0.5 * (s * (1.0 / C_));
  }
  __syncthreads();

  const int t0 = tid * 4;
  double acc[4][4];
#pragma unroll
  for (int xi = 0; xi < 4; ++xi)
#pragma unroll
    for (int k = 0; k < 4; ++k) acc[xi][k] = 0.0;

  const float4* yp = (const float4*)(y + (size_t)b * C_ * TY_) + tid;
#pragma unroll 4
  for (int c = 0; c < C_; ++c) {
    float4 yv = yp[c * (TY_ / 4)];
    double y0 = yv.x, y1 = yv.y, y2 = yv.z, y3 = yv.w;
#pragma unroll
    for (int xi = 0; xi < 4; ++xi) {
      double m = s_mu[xi][c], w = s_w[xi][c];
      double d0 = y0 - m, d1 = y1 - m, d2 = y2 - m, d3 = y3 - m;
      acc[xi][0] = fma(d0 * d0, w, acc[xi][0]);
      acc[xi][1] = fma(d1 * d1, w, acc[xi][1]);
      acc[xi][2] = fma(d2 * d2, w, acc[xi][2]);
      acc[xi][3] = fma(d3 * d3, w, acc[xi][3]);
    }
  }

  const int xlen = xlp[b], ylen = ylp[b];
#pragma unroll
  for (int xi = 0; xi < 4; ++xi) {
    int x = x0 + xi;
    double c0 = s_t0[xi];
    float r[4];
#pragma unroll
    for (int k = 0; k < 4; ++k)
      r[k] = (float)(acc[xi][k] * (-0.5 / C_) + c0);
    *(float4*)&logp_out[((size_t)(b * TX_ + x)) * TY_ + t0] =
        make_float4(r[0], r[1], r[2], r[3]);
    bool xm = x < xlen;
#pragma unroll
    for (int k = 0; k < 4; ++k)
      tile[t0 + k][xi] = (xm && (t0 + k) < ylen) ? r[k] : NEGF;
  }
  __syncthreads();

  float* dst = lpT + (size_t)b * TY_ * TX_ + x0;
  const float4* tp = (const float4*)tile;
#pragma unroll
  for (int k = 0; k < 4; ++k) {
    int t = tid + 256 * k;           // consecutive lanes -> consecutive t
    *(float4*)&dst[(size_t)t * TX_] = tp[t];
  }
}

// ---------------------------------------------------------------------------
// Kernel B: Viterbi DP, producer-consumer. Wave 1 stages the next 16 columns
// into the LDS double buffer; wave 0 runs the DP: per chunk, all 16 column
// ds_read_b128 are issued into cl[16] (fine-grained lgkm waits), the lane
// shift is DPP (no LDS), so iterations run at VALU speed.
// LDS (64KB): words [0,8192) = column ring (2 x 16 cols x 1KB), reused for
// dur[] after the main loop; words [8192,16384) = diag bits at
// BITS_OFF + w*256 + x  (uint4 write per lane per 32 cols).
// ---------------------------------------------------------------------------
__global__ __launch_bounds__(128) void k_dp(
    const float* __restrict__ lpT, const int* __restrict__ xlp,
    const int* __restrict__ ylp, float* __restrict__ dr_out,
    int* __restrict__ cum_ws, int* __restrict__ xt_ws)
{
  const int b = blockIdx.x;
  const int lane = threadIdx.x & 63;
  const int wid  = threadIdx.x >> 6;
  __shared__ uint32_t smem[16384];           // 64 KB
  float* smemf = (float*)smem;
#define BITS_OFF 8192

  const float* gb = lpT + (size_t)b * TY_ * TX_;  // column t at gb + t*TX_

  // prologue: producer fills buffer 0 with chunk 0 (cols 0..15)
  if (wid == 1) {
    const float4* src = (const float4*)gb + lane;
    float4 v[16];
#pragma unroll
    for (int i = 0; i < 16; ++i) v[i] = src[i * 64];
#pragma unroll
    for (int i = 0; i < 16; ++i)
      *(float4*)&smemf[i * 256 + 4 * lane] = v[i];
  }
  __syncthreads();

  double v0 = (lane == 0) ? 0.0 : NEGD, v1 = NEGD, v2 = NEGD, v3 = NEGD;
  double sh = NEGD;                     // lane-shifted v3 from previous col
  uint32_t b0 = 0, b1 = 0, b2 = 0, b3 = 0;

  for (int c = 0; c < TY_ / 16; ++c) {
    if (wid == 1) {
      // produce chunk c+1 into buffer (c+1)&1; barrier drains the writes
      if (c + 1 < TY_ / 16) {
        const float4* src =
            (const float4*)(gb + (size_t)(c + 1) * 16 * TX_) + lane;
        float4 v[16];
#pragma unroll
        for (int i = 0; i < 16; ++i) v[i] = src[i * 64];
        const uint32_t nbase = ((c + 1) & 1) * 4096;
#pragma unroll
        for (int i = 0; i < 16; ++i)
          *(float4*)&smemf[nbase + i * 256 + 4 * lane] = v[i];
      }
    } else if (wid == 0) {
      const uint32_t rbase = (c & 1) * 4096;
      float4 cl[16];
#pragma unroll
      for (int i = 0; i < 16; ++i)
        cl[i] = *(const float4*)&smemf[rbase + i * 256 + 4 * lane];
#pragma unroll
      for (int i = 0; i < 16; ++i) {
        const int t = c * 16 + i;
        const double vs0 = sh;          // lane 0 already NEGD via DPP old
        uint32_t bit = 1u << (t & 31);
        if (vs0 > v0) b0 |= bit;        // diag = v_shift > v (pre-update)
        if (v0 > v1)  b1 |= bit;
        if (v1 > v2)  b2 |= bit;
        if (v2 > v3)  b3 |= bit;
        double nv3 = (double)cl[i].w + fmax(v3, v2);
        sh = dpp_shr1_negfill(nv3);     // pure VALU lane shift
        double nv2 = (double)cl[i].z + fmax(v2, v1);
        double nv1 = (double)cl[i].y + fmax(v1, v0);
        double nv0 = (double)cl[i].x + fmax(v0, vs0);
        v0 = nv0; v1 = nv1; v2 = nv2; v3 = nv3;
        if ((t & 31) == 31) {
          int w = t >> 5;
          uint4 pk; pk.x = b0; pk.y = b1; pk.z = b2; pk.w = b3;
          *(uint4*)&smem[BITS_OFF + w * 256 + 4 * lane] = pk;
          b0 = b1 = b2 = b3 = 0;
        }
      }
    }
    __syncthreads();
  }

  // dur[] aliases the (now dead) column ring
  uint32_t* dur = smem;
  for (int j = threadIdx.x; j < TX_; j += 128) dur[j] = 0;
  __syncthreads();

  const int xlen = xlp[b], ylen = ylp[b];
  if (threadIdx.x == 0) {
    int idx = xlen - 1;
    int t = ylen - 1;
    while (t >= 0) {
      if (idx == 0) { dur[0] += (uint32_t)(t + 1); break; }
      int w = t >> 5, rr = t & 31;
      uint32_t word = smem[BITS_OFF + w * 256 + idx];
      word &= (rr == 31) ? 0xffffffffu : ((1u << (rr + 1)) - 1u);
      while (word == 0 && w > 0) {
        --w;
        word = smem[BITS_OFF + w * 256 + idx];
      }
      if (word == 0) { dur[idx] += (uint32_t)(t + 1); break; }
      int bitpos = 31 - __builtin_clz(word);
      int tp = (w << 5) | bitpos;          // step where diag fires -> decrement
      dur[idx] += (uint32_t)(t - tp + 1);
      --idx;
      t = tp - 1;
    }
  }
  __syncthreads();

  if (wid == 0) {
    // wave-wide inclusive scan of durations -> cum, dr, and t->x scatter map
    uint32_t d0 = dur[4 * lane], d1 = dur[4 * lane + 1];
    uint32_t d2 = dur[4 * lane + 2], d3 = dur[4 * lane + 3];
    uint32_t own = d0 + d1 + d2 + d3;
    uint32_t s = own;
#pragma unroll
    for (int off = 1; off < 64; off <<= 1) {
      uint32_t n = __shfl_up(s, off);
      if (lane >= off) s += n;
    }
    uint32_t base = s - own;
    uint32_t c0 = base + d0, c1 = c0 + d1, c2 = c1 + d2, c3 = c2 + d3;
    int x = 4 * lane;
    cum_ws[b * TX_ + x]     = (int)c0;
    cum_ws[b * TX_ + x + 1] = (int)c1;
    cum_ws[b * TX_ + x + 2] = (int)c2;
    cum_ws[b * TX_ + x + 3] = (int)c3;
    dr_out[b * TX_ + x]     = (float)d0;
    dr_out[b * TX_ + x + 1] = (float)d1;
    dr_out[b * TX_ + x + 2] = (float)d2;
    dr_out[b * TX_ + x + 3] = (float)d3;
    int* xt = xt_ws + b * TY_;
    for (uint32_t t = c0 - d0; t < c0; ++t) xt[t] = x;
    for (uint32_t t = c1 - d1; t < c1; ++t) xt[t] = x + 1;
    for (uint32_t t = c2 - d2; t < c2; ++t) xt[t] = x + 2;
    for (uint32_t t = c3 - d3; t < c3; ++t) xt[t] = x + 3;
  }
}

// ---------------------------------------------------------------------------
// Kernel C (fused epilogue): blocks [0,TX) write attn rows from cum;
// blocks [TX,TX+H) gather o_en_ex[b,h,t] = t<ylen ? en[b,h,xt[b,t]] : 0.
// ---------------------------------------------------------------------------
__global__ __launch_bounds__(256) void k_epi(
    const int* __restrict__ cum_ws, const int* __restrict__ xt_ws,
    const float* __restrict__ en, const int* __restrict__ ylp,
    float* __restrict__ attn, float* __restrict__ oen)
{
  const int b = blockIdx.y, bx = blockIdx.x, tid = threadIdx.x;
  __shared__ float row[TX_];
  if (bx < TX_) {
    const int x = bx;
    int hi = cum_ws[b * TX_ + x];
    int lo = (x > 0) ? cum_ws[b * TX_ + x - 1] : 0;
    int t0 = tid * 4;
    float4 v;
    v.x = (t0     >= lo && t0     < hi) ? 1.f : 0.f;
    v.y = (t0 + 1 >= lo && t0 + 1 < hi) ? 1.f : 0.f;
    v.z = (t0 + 2 >= lo && t0 + 2 < hi) ? 1.f : 0.f;
    v.w = (t0 + 3 >= lo && t0 + 3 < hi) ? 1.f : 0.f;
    *(float4*)&attn[((size_t)(b * TX_ + x)) * TY_ + t0] = v;
  } else {
    const int h = bx - TX_;
    row[tid] = en[((size_t)(b * H_ + h)) * TX_ + tid];
    __syncthreads();
    const int ylen = ylp[b];
    int t0 = tid * 4;
    int4 xi = *(const int4*)&xt_ws[b * TY_ + t0];
    float4 v;
    v.x = (t0     < ylen) ? row[xi.x & (TX_ - 1)] : 0.f;
    v.y = (t0 + 1 < ylen) ? row[xi.y & (TX_ - 1)] : 0.f;
    v.z = (t0 + 2 < ylen) ? row[xi.z & (TX_ - 1)] : 0.f;
    v.w = (t0 + 3 < ylen) ? row[xi.w & (TX_ - 1)] : 0.f;
    *(float4*)&oen[((size_t)(b * H_ + h)) * TY_ + t0] = v;
  }
}

extern "C" void kernel_launch(void* const* d_in, const int* in_sizes, int n_in,
                              void* d_out, int out_size, void* d_ws, size_t ws_size,
                              hipStream_t stream)
{
  const float* en = (const float*)d_in[0];
  const float* mu = (const float*)d_in[1];
  const float* ls = (const float*)d_in[2];
  const float* y  = (const float*)d_in[3];
  const int*   xl = (const int*)d_in[4];
  const int*   yl = (const int*)d_in[5];

  float* out  = (float*)d_out;
  float* oen  = out;             // [B,H,TY]
  float* logp = out + OFF_LOGP;  // [B,TX,TY]
  float* attn = out + OFF_ATTN;  // [B,TX,TY] (doubles as lpT scratch first)
  float* dr   = out + OFF_DR;    // [B,TX]

  int* cum = (int*)d_ws;         // B*TX ints
  int* xt  = cum + B_ * TX_;     // B*TY ints

  k_logp<<<dim3(TX_ / 4, B_),   256, 0, stream>>>(mu, ls, y, xl, yl, logp, attn);
  k_dp  <<<B_,                  128, 0, stream>>>(attn, xl, yl, dr, cum, xt);
  k_epi <<<dim3(TX_ + H_, B_),  256, 0, stream>>>(cum, xt, en, yl, attn, oen);
}